// Round 2
// baseline (494.803 us; speedup 1.0000x reference)
//
#include <hip/hip_runtime.h>
#include <math.h>

// downprompt R1: 8 lanes/row x 8 rows/wave.
// lane l -> (r = l>>3 : row in group, c = l&7 : column chunk).
// k-loop (8 iters) covers cols k*32 + c*4 .. +3  (float4).
// Reduction over 8 lanes = 3 butterfly stages (offsets 1,2,4) shared by
// 8 rows -> 3 shuffle+add per row (was 48).
// coef[256] precomputed per block in LDS; ave re-read per k (7KB, L1-hot).

#define NCLS 7

__device__ __forceinline__ float elu1(float x) {
    return x > 0.0f ? x : __expf(x) - 1.0f;
}

__global__ __launch_bounds__(256) void downprompt_kernel(
    const float* __restrict__ seq,
    const float* __restrict__ seq1,
    const float* __restrict__ prompt,
    const float* __restrict__ w_np,
    const float* __restrict__ w_ds,
    const float* __restrict__ w_df,
    const float* __restrict__ ave,
    float* __restrict__ out,
    int N)
{
    __shared__ float s_coef[256];
    __shared__ float s_rna[NCLS];

    const int tid = threadIdx.x;

    // ---- per-block setup ----
    {   // coef[d] = a*(1+elu((w_np@prompt)[d])) + b*w_ds[d], one d per thread
        const float a  = w_df[0], b = w_df[1];
        const float w0 = w_np[0], w1 = w_np[1], w2 = w_np[2];
        const float pd = w0 * prompt[tid] + w1 * prompt[256 + tid]
                       + w2 * prompt[512 + tid];
        s_coef[tid] = a * (1.0f + elu1(pd)) + b * w_ds[tid];
    }
    if (tid < NCLS) {   // 1/||ave_c||, one class per thread (serial, L1-hot)
        const float4* av4 = (const float4*)(ave + tid * 256);
        float s = 0.0f;
#pragma unroll
        for (int i = 0; i < 64; ++i) {
            const float4 v = av4[i];
            s += v.x * v.x + v.y * v.y + v.z * v.z + v.w * v.w;
        }
        s_rna[tid] = rsqrtf(s);
    }
    __syncthreads();

    const int lane = tid & 63;
    const int r = lane >> 3;          // row within group of 8
    const int c = lane & 7;           // column chunk within row
    const int wv  = blockIdx.x * (blockDim.x >> 6) + (tid >> 6);
    const int nwv = gridDim.x * (blockDim.x >> 6);
    const int ngroups = (N + 7) >> 3;

    float rna[NCLS];
#pragma unroll
    for (int k = 0; k < NCLS; ++k) rna[k] = s_rna[k];

    for (int g = wv; g < ngroups; g += nwv) {
        const int rowv = (g << 3) + r;
        const int row  = rowv < N ? rowv : N - 1;   // clamp (N%8==0 normally)
        const float* srow = seq  + (size_t)row * 256;
        const float* trow = seq1 + (size_t)row * 256;

        float acc[8];
#pragma unroll
        for (int k = 0; k < 8; ++k) acc[k] = 0.0f;

#pragma unroll
        for (int k = 0; k < 8; ++k) {
            const int col = k * 32 + c * 4;
            const float4 s  = *(const float4*)(srow + col);
            const float4 t  = *(const float4*)(trow + col);
            const float4 cf = *(const float4*)(s_coef + col);

            const float x0 = elu1(cf.x * s.x) + 0.1f * t.x;
            const float x1 = elu1(cf.y * s.y) + 0.1f * t.y;
            const float x2 = elu1(cf.z * s.z) + 0.1f * t.z;
            const float x3 = elu1(cf.w * s.w) + 0.1f * t.w;

#pragma unroll
            for (int cl = 0; cl < NCLS; ++cl) {
                const float4 av = *(const float4*)(ave + cl * 256 + col);
                acc[cl] += x0 * av.x + x1 * av.y + x2 * av.z + x3 * av.w;
            }
            acc[7] += x0 * x0 + x1 * x1 + x2 * x2 + x3 * x3;
        }

        // 3-stage butterfly within each 8-lane row group (offsets 1,2,4)
#pragma unroll
        for (int off = 1; off < 8; off <<= 1) {
#pragma unroll
            for (int k = 0; k < 8; ++k)
                acc[k] += __shfl_xor(acc[k], off, 64);
        }

        // softmax over 7 classes, computed redundantly per lane
        const float rnr = rsqrtf(fmaxf(acc[7], 1e-30f));
        float sims[NCLS];
        float m = -INFINITY;
#pragma unroll
        for (int cl = 0; cl < NCLS; ++cl) {
            sims[cl] = acc[cl] * rna[cl] * rnr;
            m = fmaxf(m, sims[cl]);
        }
        float sum = 0.0f, mye = 0.0f;
#pragma unroll
        for (int cl = 0; cl < NCLS; ++cl) {
            const float e = __expf(sims[cl] - m);
            sum += e;
            if (c == cl) mye = e;
        }
        if (c < NCLS && rowv < N)
            out[(size_t)rowv * NCLS + c] = mye * __builtin_amdgcn_rcpf(sum);
    }
}

extern "C" void kernel_launch(void* const* d_in, const int* in_sizes, int n_in,
                              void* d_out, int out_size, void* d_ws, size_t ws_size,
                              hipStream_t stream) {
    const float* seq    = (const float*)d_in[0];
    const float* seq1   = (const float*)d_in[1];
    const float* prompt = (const float*)d_in[2];
    const float* w_np   = (const float*)d_in[3];
    const float* w_ds   = (const float*)d_in[4];
    const float* w_df   = (const float*)d_in[5];
    const float* ave    = (const float*)d_in[6];
    float* out = (float*)d_out;

    const int N = in_sizes[0] / 256;   // 200000 -> 25000 row-groups

    // 1563 blocks x 4 waves = 6252 waves; 25000 groups -> every wave does
    // exactly 4 (last 8 waves do 3): balanced tail, 3% setup overhead.
    downprompt_kernel<<<1563, 256, 0, stream>>>(seq, seq1, prompt, w_np, w_ds,
                                                w_df, ave, out, N);
}

// Round 3
// 447.530 us; speedup vs baseline: 1.1056x; 1.1056x over previous
//
#include <hip/hip_runtime.h>
#include <math.h>

// downprompt R2: one ROW PER LANE (64 rows/wave), zero cross-lane ops.
// At k-iter, all lanes read the same coef/ave values -> wave-uniform ->
// scalar loads (s_load) from a packed table in d_ws:
//   ws[k*32 + 0..3]            = coef[k*4 .. k*4+3]
//   ws[k*32 + 4 + cl*4 + j]    = ave[cl][k*4+j]      (cl = 0..6)
//   ws[2048 + cl]              = 1/||ave_cl||
// seq/seq1 reads are lane-scattered (1KB row stride) but line-complete:
// TA cost ~32 lines/row, far under the HBM/L3 stream floor.

#define NCLS 7

__device__ __forceinline__ float elu1(float x) {
    return x > 0.0f ? x : __expf(x) - 1.0f;
}

__global__ __launch_bounds__(256) void setup_kernel(
    const float* __restrict__ prompt,
    const float* __restrict__ w_np,
    const float* __restrict__ w_ds,
    const float* __restrict__ w_df,
    const float* __restrict__ ave,
    float* __restrict__ ws)
{
    __shared__ float part[NCLS * 32];
    const int tid = threadIdx.x;

    // coef[d] = a*(1+elu((w_np@prompt)[d])) + b*w_ds[d]; d = tid
    {
        const float a = w_df[0], b = w_df[1];
        const float w0 = w_np[0], w1 = w_np[1], w2 = w_np[2];
        const float pd = w0 * prompt[tid] + w1 * prompt[256 + tid]
                       + w2 * prompt[512 + tid];
        const float coef = a * (1.0f + elu1(pd)) + b * w_ds[tid];
        ws[(tid >> 2) * 32 + (tid & 3)] = coef;
    }
    // pack ave interleaved: ws[k*32 + 4 + cl*4 + j] = ave[cl*256 + k*4 + j]
    for (int i = tid; i < NCLS * 256; i += 256) {
        const int cl = i >> 8, d = i & 255;
        ws[(d >> 2) * 32 + 4 + cl * 4 + (d & 3)] = ave[i];
    }
    // rna[cl] = 1/||ave_cl||: 32 threads/class partial, then reduce
    const int cl = tid >> 5, j = tid & 31;
    if (cl < NCLS) {
        const float* r = ave + cl * 256 + j * 8;
        float s = 0.0f;
#pragma unroll
        for (int i = 0; i < 8; ++i) s += r[i] * r[i];
        part[cl * 32 + j] = s;
    }
    __syncthreads();
    if (tid < NCLS) {
        float s = 0.0f;
#pragma unroll
        for (int i = 0; i < 32; ++i) s += part[tid * 32 + i];
        ws[2048 + tid] = rsqrtf(s);
    }
}

__global__ __launch_bounds__(256) void downprompt_kernel(
    const float* __restrict__ seq,
    const float* __restrict__ seq1,
    const float* __restrict__ ws,
    float* __restrict__ out,
    int N)
{
    const int lane = threadIdx.x & 63;
    const int w = blockIdx.x * (blockDim.x >> 6) + (threadIdx.x >> 6);
    const int row = (w << 6) + lane;
    if (row >= N) return;

    const float* __restrict__ srow = seq  + (size_t)row * 256;
    const float* __restrict__ trow = seq1 + (size_t)row * 256;

    float acc[NCLS + 1];
#pragma unroll
    for (int i = 0; i <= NCLS; ++i) acc[i] = 0.0f;

#pragma unroll 4
    for (int k = 0; k < 64; ++k) {
        const float4 s = *(const float4*)(srow + k * 4);
        const float4 t = *(const float4*)(trow + k * 4);
        const float* u = ws + k * 32;          // wave-uniform -> s_load

        const float x0 = fmaf(0.1f, t.x, elu1(u[0] * s.x));
        const float x1 = fmaf(0.1f, t.y, elu1(u[1] * s.y));
        const float x2 = fmaf(0.1f, t.z, elu1(u[2] * s.z));
        const float x3 = fmaf(0.1f, t.w, elu1(u[3] * s.w));

#pragma unroll
        for (int cl = 0; cl < NCLS; ++cl) {
            const float* a = u + 4 + cl * 4;   // uniform
            acc[cl] += x0 * a[0] + x1 * a[1] + x2 * a[2] + x3 * a[3];
        }
        acc[NCLS] += x0 * x0 + x1 * x1 + x2 * x2 + x3 * x3;
    }

    // per-lane (= per-row) cosine-sim + softmax; rna uniform
    const float rnr = rsqrtf(fmaxf(acc[NCLS], 1e-30f));
    float sims[NCLS];
    float m = -INFINITY;
#pragma unroll
    for (int cl = 0; cl < NCLS; ++cl) {
        sims[cl] = acc[cl] * ws[2048 + cl] * rnr;
        m = fmaxf(m, sims[cl]);
    }
    float e[NCLS], sum = 0.0f;
#pragma unroll
    for (int cl = 0; cl < NCLS; ++cl) {
        e[cl] = __expf(sims[cl] - m);
        sum += e[cl];
    }
    const float rs = __builtin_amdgcn_rcpf(sum);
    float* orow = out + (size_t)row * NCLS;
#pragma unroll
    for (int cl = 0; cl < NCLS; ++cl)
        orow[cl] = e[cl] * rs;
}

extern "C" void kernel_launch(void* const* d_in, const int* in_sizes, int n_in,
                              void* d_out, int out_size, void* d_ws, size_t ws_size,
                              hipStream_t stream) {
    const float* seq    = (const float*)d_in[0];
    const float* seq1   = (const float*)d_in[1];
    const float* prompt = (const float*)d_in[2];
    const float* w_np   = (const float*)d_in[3];
    const float* w_ds   = (const float*)d_in[4];
    const float* w_df   = (const float*)d_in[5];
    const float* ave    = (const float*)d_in[6];
    float* out = (float*)d_out;
    float* ws  = (float*)d_ws;   // needs (2048 + 7) floats

    const int N = in_sizes[0] / 256;   // 200000

    setup_kernel<<<1, 256, 0, stream>>>(prompt, w_np, w_ds, w_df, ave, ws);

    const int nwaves = (N + 63) >> 6;          // 3125
    const int blocks = (nwaves + 3) >> 2;      // 782 (4 waves/block)
    downprompt_kernel<<<blocks, 256, 0, stream>>>(seq, seq1, ws, out, N);
}